// Round 6
// baseline (272.416 us; speedup 1.0000x reference)
//
#include <hip/hip_runtime.h>

typedef __attribute__((ext_vector_type(8))) short short8;
typedef __attribute__((ext_vector_type(4))) float float4v;
typedef __attribute__((ext_vector_type(4))) int int4v;

#define E_EDGES 300000
#define EPB 128                                 // edges per block (32 per wave)
#define NBLK ((E_EDGES + EPB - 1) / EPB)        // 2344 blocks per edge type
#define TAB_ELEMS 12800000                      // 100000 nodes x 128 feats

__device__ __forceinline__ short f2bf(float f) {
    unsigned u = __float_as_uint(f);
    return (short)((u + 0x7FFFu + ((u >> 16) & 1u)) >> 16);
}
__device__ __forceinline__ unsigned pk_bf16(float a, float b) {
    unsigned ua = __float_as_uint(a), ub = __float_as_uint(b);
    ua += 0x7FFFu + ((ua >> 16) & 1u);
    ub += 0x7FFFu + ((ub >> 16) & 1u);
    return __builtin_amdgcn_perm(ub, ua, 0x07060302);
}
__device__ __forceinline__ void cp16(const void* g, void* l) {
    __builtin_amdgcn_global_load_lds(
        (const __attribute__((address_space(1))) unsigned int*)g,
        (__attribute__((address_space(3))) unsigned int*)l, 16, 0, 0);
}

// ws layout (shorts):
//   [0..98304)            weight tiles [n][k] in 64-k tiles, chunk-XOR swizzled
//   [98304..+12.8M)       user_emb bf16
//   [..+25.6M)            item_emb bf16
__global__ void prep_all(const float* __restrict__ ue, const float* __restrict__ ie,
                         const float* __restrict__ Wbi_ui, const float* __restrict__ W1_ui,
                         const float* __restrict__ Wbi_iu, const float* __restrict__ W1_iu,
                         short* __restrict__ ws) {
    __shared__ short tr[64 * 68];
    const int t = blockIdx.y;
    const int tid = threadIdx.x;
    if (blockIdx.x < 1024) {                    // ---- streaming table conversion ----
        const float* src = t ? ie : ue;
        short* dst = ws + 98304 + (size_t)t * TAB_ELEMS;
        const int stride = 1024 * 256;
        for (int g = blockIdx.x * 256 + tid; g < TAB_ELEMS / 8; g += stride) {
            const float* p = src + (size_t)g * 8;
            float4v v0 = ((const float4v*)p)[0];
            float4v v1 = ((const float4v*)p)[1];
            int4v w = { (int)pk_bf16(v0[0], v0[1]), (int)pk_bf16(v0[2], v0[3]),
                        (int)pk_bf16(v1[0], v1[1]), (int)pk_bf16(v1[2], v1[3]) };
            *(int4v*)(dst + (size_t)g * 8) = w;
        }
        return;
    }
    // ---- weight transpose + swizzle (12 tiles per type) ----
    const int m = blockIdx.x - 1024;            // 0..11
    const float* W; int k0, n0, obase;
    if (m < 8) {                                // Wbi (K=256, N=128)
        int kt = m >> 1, nh = m & 1;
        W = t ? Wbi_iu : Wbi_ui; k0 = kt * 64; n0 = nh * 64;
        obase = t * 32768 + kt * 8192;
    } else {                                    // W1 (K=128, N=128)
        int mm = m - 8; int kt = mm >> 1, nh = mm & 1;
        W = t ? W1_iu : W1_ui; k0 = kt * 64; n0 = nh * 64;
        obase = 65536 + t * 16384 + kt * 8192;
    }
    for (int it = 0; it < 16; ++it) {
        int flat = it * 256 + tid;
        int kk = flat >> 6, nn = flat & 63;
        tr[nn * 68 + kk] = f2bf(W[(size_t)(k0 + kk) * 128 + n0 + nn]);
    }
    __syncthreads();
    for (int it = 0; it < 16; ++it) {
        int flat = it * 256 + tid;
        int nn = flat >> 6, kk = flat & 63;
        int n = n0 + nn;
        ws[obase + n * 64 + (kk ^ ((n & 7) << 3))] = tr[nn * 68 + kk];
    }
}

template<bool BF16G>
__launch_bounds__(256, 4)
__global__ void edge_decoder(
    const float* __restrict__ user_emb, const float* __restrict__ item_emb,
    const int* __restrict__ ei_ui, const int* __restrict__ ei_iu,
    const float* __restrict__ b_bi_ui, const float* __restrict__ b1_ui,
    const float* __restrict__ W2_ui, const float* __restrict__ b2_ui,
    const float* __restrict__ b_bi_iu, const float* __restrict__ b1_iu,
    const float* __restrict__ W2_iu, const float* __restrict__ b2_iu,
    const short* __restrict__ ws, const short* __restrict__ tab,
    float* __restrict__ out)
{
    __shared__ short Blds[128 * 64];            // 16384 B weight tile (single buffer)
    __shared__ short Hlds[4 * 16 * 136];        // 17408 B per-wave H (16 rows, reused for mt=0,1)

    const int type = blockIdx.y;
    const int e0 = blockIdx.x * EPB;
    const int tid = threadIdx.x;
    const int wave = tid >> 6, lane = tid & 63;
    const int q = lane >> 4, ln = lane & 15;

    const int*   ei   = type ? ei_iu : ei_ui;
    const float* bbi  = type ? b_bi_iu : b_bi_ui;
    const float* b1v  = type ? b1_iu : b1_ui;
    const float* W2v  = type ? W2_iu : W2_ui;
    const float* b2v  = type ? b2_iu : b2_ui;
    const short* WbiT = ws + type * 32768;
    const short* W1T  = ws + 65536 + type * 16384;

    // DMA weight tile 0 (overlaps the gather below)
    for (int c = 0; c < 4; ++c)
        cp16(WbiT + c * 2048 + tid * 8, Blds + c * 2048 + tid * 8);

    // gather A fragments: a[mt][ks] elem j = e_cat[edge][32*ks + 8*q + j]
    short8 a[2][8];
    if (BF16G) {
        for (int mt = 0; mt < 2; ++mt) {
            int erow = e0 + wave * 32 + mt * 16 + ln;
            int safe = (erow < E_EDGES) ? erow : 0;
            const short* sp = tab + (size_t)(type ? TAB_ELEMS : 0) + (size_t)ei[safe] * 128;
            const short* dp = tab + (size_t)(type ? 0 : TAB_ELEMS) + (size_t)ei[E_EDGES + safe] * 128;
            for (int ks = 0; ks < 4; ++ks)
                a[mt][ks] = *(const short8*)(sp + ks * 32 + q * 8);
            for (int ks = 4; ks < 8; ++ks)
                a[mt][ks] = *(const short8*)(dp + (ks - 4) * 32 + q * 8);
        }
    } else {
        const float* srcT = type ? item_emb : user_emb;
        const float* dstT = type ? user_emb : item_emb;
        for (int mt = 0; mt < 2; ++mt) {
            int erow = e0 + wave * 32 + mt * 16 + ln;
            int safe = (erow < E_EDGES) ? erow : 0;
            int si = ei[safe], di = ei[E_EDGES + safe];
            for (int ks = 0; ks < 8; ++ks) {
                const float* p = (ks < 4) ? (srcT + (size_t)si * 128 + ks * 32 + q * 8)
                                          : (dstT + (size_t)di * 128 + (ks - 4) * 32 + q * 8);
                float4v v0 = ((const float4v*)p)[0];
                float4v v1 = ((const float4v*)p)[1];
                int4v w = { (int)pk_bf16(v0[0], v0[1]), (int)pk_bf16(v0[2], v0[3]),
                            (int)pk_bf16(v1[0], v1[1]), (int)pk_bf16(v1[2], v1[3]) };
                a[mt][ks] = *(short8*)&w;
            }
        }
    }

    // acc init = bias (column-only -> all 4 row-elems identical)
    float4v acc[2][8];
    for (int nt = 0; nt < 8; ++nt) {
        float bb = bbi[nt * 16 + ln];
        acc[0][nt] = (float4v){bb, bb, bb, bb};
        acc[1][nt] = acc[0][nt];
    }

    const int swz = (ln & 7) << 3;

    // ---- Layer 1: K=256, 4 LDS tiles of 64; each B-frag feeds 2 M-tiles ----
    for (int kt = 0; kt < 4; ++kt) {
        __syncthreads();                        // tile kt resident
        for (int ks2 = 0; ks2 < 2; ++ks2) {
            int ka = (ks2 * 32 + q * 8) ^ swz;
            int ks = kt * 2 + ks2;
            for (int nt = 0; nt < 8; ++nt) {
                short8 bf = *(const short8*)&Blds[(nt * 16 + ln) * 64 + ka];
                acc[0][nt] = __builtin_amdgcn_mfma_f32_16x16x32_bf16(a[0][ks], bf, acc[0][nt], 0, 0, 0);
                acc[1][nt] = __builtin_amdgcn_mfma_f32_16x16x32_bf16(a[1][ks], bf, acc[1][nt], 0, 0, 0);
            }
        }
        __syncthreads();                        // all waves done reading tile kt
        const short* nxt = (kt < 3) ? (WbiT + (kt + 1) * 8192) : W1T;
        for (int c = 0; c < 4; ++c)
            cp16(nxt + c * 2048 + tid * 8, Blds + c * 2048 + tid * 8);
    }

    // ---- Epilogue 1: ELU -> bf16 H, one 16-row per-wave buffer reused for mt=0,1 ----
    // C/D layout: col = ln (+16*nt), row = q*4 + r
    short* Hw = Hlds + wave * (16 * 136);
    short8 a2[2][4];
    for (int mt = 0; mt < 2; ++mt) {
        for (int nt = 0; nt < 8; ++nt) {
            int col = nt * 16 + ln;
            float4v v = acc[mt][nt];
            for (int r = 0; r < 4; ++r) {
                float x = v[r];
                float h = x > 0.f ? x : (__expf(x) - 1.f);
                Hw[(q * 4 + r) * 136 + col] = f2bf(h);
            }
        }
        // same-wave RAW on Hw; in-order DS + compiler lgkmcnt keeps this safe
        for (int ks = 0; ks < 4; ++ks)
            a2[mt][ks] = *(const short8*)&Hw[ln * 136 + ks * 32 + q * 8];
        // next mt iteration overwrites Hw only after these reads (same-wave WAR, in-order DS)
    }

    for (int nt = 0; nt < 8; ++nt) {
        float bb = b1v[nt * 16 + ln];
        acc[0][nt] = (float4v){bb, bb, bb, bb};
        acc[1][nt] = acc[0][nt];
    }

    // ---- Layer 2: K=128, 2 LDS tiles of 64 ----
    for (int kt = 0; kt < 2; ++kt) {
        __syncthreads();
        for (int ks2 = 0; ks2 < 2; ++ks2) {
            int ka = (ks2 * 32 + q * 8) ^ swz;
            int ks = kt * 2 + ks2;
            for (int nt = 0; nt < 8; ++nt) {
                short8 bf = *(const short8*)&Blds[(nt * 16 + ln) * 64 + ka];
                acc[0][nt] = __builtin_amdgcn_mfma_f32_16x16x32_bf16(a2[0][ks], bf, acc[0][nt], 0, 0, 0);
                acc[1][nt] = __builtin_amdgcn_mfma_f32_16x16x32_bf16(a2[1][ks], bf, acc[1][nt], 0, 0, 0);
            }
        }
        __syncthreads();
        if (kt == 0)
            for (int c = 0; c < 4; ++c)
                cp16(W1T + 8192 + c * 2048 + tid * 8, Blds + c * 2048 + tid * 8);
    }

    // ---- Epilogue 2: ELU, dot W2, 16-lane reduce, sigmoid, store ----
    for (int mt = 0; mt < 2; ++mt) {
        float s0 = 0.f, s1 = 0.f, s2 = 0.f, s3 = 0.f;
        for (int nt = 0; nt < 8; ++nt) {
            float wv = W2v[nt * 16 + ln];
            float4v v = acc[mt][nt];
            float x;
            x = v[0]; x = x > 0.f ? x : (__expf(x) - 1.f); s0 += x * wv;
            x = v[1]; x = x > 0.f ? x : (__expf(x) - 1.f); s1 += x * wv;
            x = v[2]; x = x > 0.f ? x : (__expf(x) - 1.f); s2 += x * wv;
            x = v[3]; x = x > 0.f ? x : (__expf(x) - 1.f); s3 += x * wv;
        }
        for (int off = 1; off < 16; off <<= 1) {
            s0 += __shfl_xor(s0, off);
            s1 += __shfl_xor(s1, off);
            s2 += __shfl_xor(s2, off);
            s3 += __shfl_xor(s3, off);
        }
        if (ln < 4) {
            float sv = (ln == 0) ? s0 : (ln == 1) ? s1 : (ln == 2) ? s2 : s3;
            int e = e0 + wave * 32 + mt * 16 + q * 4 + ln;
            if (e < E_EDGES) {
                float z = sv + b2v[0];
                out[type * E_EDGES + e] = 1.f / (1.f + __expf(-z));
            }
        }
    }
}

extern "C" void kernel_launch(void* const* d_in, const int* in_sizes, int n_in,
                              void* d_out, int out_size, void* d_ws, size_t ws_size,
                              hipStream_t stream) {
    const float* user_emb = (const float*)d_in[0];
    const float* item_emb = (const float*)d_in[1];
    const int*   ei_ui    = (const int*)d_in[2];
    const int*   ei_iu    = (const int*)d_in[3];
    const float* W_bi_ui  = (const float*)d_in[4];
    const float* b_bi_ui  = (const float*)d_in[5];
    const float* W1_ui    = (const float*)d_in[6];
    const float* b1_ui    = (const float*)d_in[7];
    const float* W2_ui    = (const float*)d_in[8];
    const float* b2_ui    = (const float*)d_in[9];
    const float* W_bi_iu  = (const float*)d_in[10];
    const float* b_bi_iu  = (const float*)d_in[11];
    const float* W1_iu    = (const float*)d_in[12];
    const float* b1_iu    = (const float*)d_in[13];
    const float* W2_iu    = (const float*)d_in[14];
    const float* b2_iu    = (const float*)d_in[15];
    short* ws  = (short*)d_ws;
    short* tab = ws + 98304;
    float* out = (float*)d_out;

    const size_t need = 98304u * 2u + (size_t)2 * TAB_ELEMS * 2u;  // 51.4 MB

    hipLaunchKernelGGL(prep_all, dim3(1036, 2), dim3(256), 0, stream,
                       user_emb, item_emb, W_bi_ui, W1_ui, W_bi_iu, W1_iu, ws);
    if (ws_size >= need) {
        edge_decoder<true><<<dim3(NBLK, 2), dim3(256), 0, stream>>>(
            user_emb, item_emb, ei_ui, ei_iu,
            b_bi_ui, b1_ui, W2_ui, b2_ui,
            b_bi_iu, b1_iu, W2_iu, b2_iu,
            ws, tab, out);
    } else {
        edge_decoder<false><<<dim3(NBLK, 2), dim3(256), 0, stream>>>(
            user_emb, item_emb, ei_ui, ei_iu,
            b_bi_ui, b1_ui, W2_ui, b2_ui,
            b_bi_iu, b1_iu, W2_iu, b2_iu,
            ws, tab, out);
    }
}

// Round 7
// 258.443 us; speedup vs baseline: 1.0541x; 1.0541x over previous
//
#include <hip/hip_runtime.h>

typedef __attribute__((ext_vector_type(8))) short short8;
typedef __attribute__((ext_vector_type(4))) float float4v;
typedef __attribute__((ext_vector_type(4))) int int4v;

#define E_EDGES 300000
#define EPB 128                                 // edges per block (32 per wave)
#define NBLK ((E_EDGES + EPB - 1) / EPB)        // 2344 blocks per edge type
#define TAB_ELEMS 12800000                      // 100000 nodes x 128 feats

__device__ __forceinline__ short f2bf(float f) {
    unsigned u = __float_as_uint(f);
    return (short)((u + 0x7FFFu + ((u >> 16) & 1u)) >> 16);
}
__device__ __forceinline__ unsigned pk_bf16(float a, float b) {
    unsigned ua = __float_as_uint(a), ub = __float_as_uint(b);
    ua += 0x7FFFu + ((ua >> 16) & 1u);
    ub += 0x7FFFu + ((ub >> 16) & 1u);
    return __builtin_amdgcn_perm(ub, ua, 0x07060302);
}
__device__ __forceinline__ void cp16(const void* g, void* l) {
    __builtin_amdgcn_global_load_lds(
        (const __attribute__((address_space(1))) unsigned int*)g,
        (__attribute__((address_space(3))) unsigned int*)l, 16, 0, 0);
}

// ws layout (shorts):
//   [0..98304)            weight tiles [n][k] in 64-k tiles, chunk-XOR swizzled
//   [98304..+12.8M)       user_emb bf16
//   [..+25.6M)            item_emb bf16
__global__ void prep_all(const float* __restrict__ ue, const float* __restrict__ ie,
                         const float* __restrict__ Wbi_ui, const float* __restrict__ W1_ui,
                         const float* __restrict__ Wbi_iu, const float* __restrict__ W1_iu,
                         short* __restrict__ ws) {
    __shared__ short tr[64 * 68];
    const int t = blockIdx.y;
    const int tid = threadIdx.x;
    if (blockIdx.x < 1024) {                    // ---- streaming table conversion ----
        const float* src = t ? ie : ue;
        short* dst = ws + 98304 + (size_t)t * TAB_ELEMS;
        const int stride = 1024 * 256;
        for (int g = blockIdx.x * 256 + tid; g < TAB_ELEMS / 8; g += stride) {
            const float* p = src + (size_t)g * 8;
            float4v v0 = ((const float4v*)p)[0];
            float4v v1 = ((const float4v*)p)[1];
            int4v w = { (int)pk_bf16(v0[0], v0[1]), (int)pk_bf16(v0[2], v0[3]),
                        (int)pk_bf16(v1[0], v1[1]), (int)pk_bf16(v1[2], v1[3]) };
            *(int4v*)(dst + (size_t)g * 8) = w;
        }
        return;
    }
    // ---- weight transpose + swizzle (12 tiles per type) ----
    const int m = blockIdx.x - 1024;            // 0..11
    const float* W; int k0, n0, obase;
    if (m < 8) {                                // Wbi (K=256, N=128)
        int kt = m >> 1, nh = m & 1;
        W = t ? Wbi_iu : Wbi_ui; k0 = kt * 64; n0 = nh * 64;
        obase = t * 32768 + kt * 8192;
    } else {                                    // W1 (K=128, N=128)
        int mm = m - 8; int kt = mm >> 1, nh = mm & 1;
        W = t ? W1_iu : W1_ui; k0 = kt * 64; n0 = nh * 64;
        obase = 65536 + t * 16384 + kt * 8192;
    }
    for (int it = 0; it < 16; ++it) {
        int flat = it * 256 + tid;
        int kk = flat >> 6, nn = flat & 63;
        tr[nn * 68 + kk] = f2bf(W[(size_t)(k0 + kk) * 128 + n0 + nn]);
    }
    __syncthreads();
    for (int it = 0; it < 16; ++it) {
        int flat = it * 256 + tid;
        int nn = flat >> 6, kk = flat & 63;
        int n = n0 + nn;
        ws[obase + n * 64 + (kk ^ ((n & 7) << 3))] = tr[nn * 68 + kk];
    }
}

template<bool BF16G>
__launch_bounds__(256, 3)
__global__ void edge_decoder(
    const float* __restrict__ user_emb, const float* __restrict__ item_emb,
    const int* __restrict__ ei_ui, const int* __restrict__ ei_iu,
    const float* __restrict__ b_bi_ui, const float* __restrict__ b1_ui,
    const float* __restrict__ W2_ui, const float* __restrict__ b2_ui,
    const float* __restrict__ b_bi_iu, const float* __restrict__ b1_iu,
    const float* __restrict__ W2_iu, const float* __restrict__ b2_iu,
    const short* __restrict__ ws, const short* __restrict__ tab,
    float* __restrict__ out)
{
    __shared__ short Blds[2][128 * 64];         // 32768 B double-buffered weight tile
    __shared__ short Hlds[4 * 16 * 136];        // 17408 B per-wave H (16 rows, reused mt=0,1)

    const int type = blockIdx.y;
    const int e0 = blockIdx.x * EPB;
    const int tid = threadIdx.x;
    const int wave = tid >> 6, lane = tid & 63;
    const int q = lane >> 4, ln = lane & 15;

    const int*   ei   = type ? ei_iu : ei_ui;
    const float* bbi  = type ? b_bi_iu : b_bi_ui;
    const float* b1v  = type ? b1_iu : b1_ui;
    const float* W2v  = type ? W2_iu : W2_ui;
    const float* b2v  = type ? b2_iu : b2_ui;
    const short* WbiT = ws + type * 32768;
    const short* W1T  = ws + 65536 + type * 16384;

    // DMA weight tile 0 -> buf0 (overlaps the gather below)
    for (int c = 0; c < 4; ++c)
        cp16(WbiT + c * 2048 + tid * 8, &Blds[0][c * 2048 + tid * 8]);

    // gather A fragments: a[mt][ks] elem j = e_cat[edge][32*ks + 8*q + j]
    short8 a[2][8];
    if (BF16G) {
        for (int mt = 0; mt < 2; ++mt) {
            int erow = e0 + wave * 32 + mt * 16 + ln;
            int safe = (erow < E_EDGES) ? erow : 0;
            const short* sp = tab + (size_t)(type ? TAB_ELEMS : 0) + (size_t)ei[safe] * 128;
            const short* dp = tab + (size_t)(type ? 0 : TAB_ELEMS) + (size_t)ei[E_EDGES + safe] * 128;
            for (int ks = 0; ks < 4; ++ks)
                a[mt][ks] = *(const short8*)(sp + ks * 32 + q * 8);
            for (int ks = 4; ks < 8; ++ks)
                a[mt][ks] = *(const short8*)(dp + (ks - 4) * 32 + q * 8);
        }
    } else {
        const float* srcT = type ? item_emb : user_emb;
        const float* dstT = type ? user_emb : item_emb;
        for (int mt = 0; mt < 2; ++mt) {
            int erow = e0 + wave * 32 + mt * 16 + ln;
            int safe = (erow < E_EDGES) ? erow : 0;
            int si = ei[safe], di = ei[E_EDGES + safe];
            for (int ks = 0; ks < 8; ++ks) {
                const float* p = (ks < 4) ? (srcT + (size_t)si * 128 + ks * 32 + q * 8)
                                          : (dstT + (size_t)di * 128 + (ks - 4) * 32 + q * 8);
                float4v v0 = ((const float4v*)p)[0];
                float4v v1 = ((const float4v*)p)[1];
                int4v w = { (int)pk_bf16(v0[0], v0[1]), (int)pk_bf16(v0[2], v0[3]),
                            (int)pk_bf16(v1[0], v1[1]), (int)pk_bf16(v1[2], v1[3]) };
                a[mt][ks] = *(short8*)&w;
            }
        }
    }

    // acc init = bias (column-only -> all 4 row-elems identical)
    float4v acc[2][8];
    for (int nt = 0; nt < 8; ++nt) {
        float bb = bbi[nt * 16 + ln];
        acc[0][nt] = (float4v){bb, bb, bb, bb};
        acc[1][nt] = acc[0][nt];
    }

    const int swz = (ln & 7) << 3;

    // ---- Layer 1: K=256, 4 tiles, double-buffered: ONE barrier per tile,
    //      DMA for tile kt+1 lands during tile kt's compute ----
    for (int kt = 0; kt < 4; ++kt) {
        __syncthreads();                        // tile kt resident in buf[kt&1]
        const short* nxt = (kt < 3) ? (WbiT + (kt + 1) * 8192) : W1T;
        short* dstb = Blds[(kt + 1) & 1];       // last read of this buf was before the sync
        for (int c = 0; c < 4; ++c)
            cp16(nxt + c * 2048 + tid * 8, dstb + c * 2048 + tid * 8);
        const short* src = Blds[kt & 1];
        for (int ks2 = 0; ks2 < 2; ++ks2) {
            int ka = (ks2 * 32 + q * 8) ^ swz;
            int ks = kt * 2 + ks2;
            for (int nt = 0; nt < 8; ++nt) {
                short8 bf = *(const short8*)&src[(nt * 16 + ln) * 64 + ka];
                acc[0][nt] = __builtin_amdgcn_mfma_f32_16x16x32_bf16(a[0][ks], bf, acc[0][nt], 0, 0, 0);
                acc[1][nt] = __builtin_amdgcn_mfma_f32_16x16x32_bf16(a[1][ks], bf, acc[1][nt], 0, 0, 0);
            }
        }
    }

    // ---- Epilogue 1: ELU -> bf16 H, wave-local 16-row buffer reused for mt=0,1 ----
    // C/D layout: col = ln (+16*nt), row = q*4 + r
    short* Hw = Hlds + wave * (16 * 136);
    short8 a2[2][4];
    for (int mt = 0; mt < 2; ++mt) {
        for (int nt = 0; nt < 8; ++nt) {
            int col = nt * 16 + ln;
            float4v v = acc[mt][nt];
            for (int r = 0; r < 4; ++r) {
                float x = v[r];
                float h = x > 0.f ? x : (__expf(x) - 1.f);
                Hw[(q * 4 + r) * 136 + col] = f2bf(h);
            }
        }
        for (int ks = 0; ks < 4; ++ks)          // same-wave RAW, lgkmcnt-guarded
            a2[mt][ks] = *(const short8*)&Hw[ln * 136 + ks * 32 + q * 8];
    }

    for (int nt = 0; nt < 8; ++nt) {
        float bb = b1v[nt * 16 + ln];
        acc[0][nt] = (float4v){bb, bb, bb, bb};
        acc[1][nt] = acc[0][nt];
    }

    // ---- Layer 2: K=128, 2 tiles; W1 t0 was DMA'd into buf0 during L1 kt=3 ----
    for (int kt = 0; kt < 2; ++kt) {
        __syncthreads();                        // W1 tile kt resident in buf[kt&1]
        if (kt == 0)
            for (int c = 0; c < 4; ++c)         // W1 t1 -> buf1, lands during t0 compute
                cp16(W1T + 8192 + c * 2048 + tid * 8, &Blds[1][c * 2048 + tid * 8]);
        const short* src = Blds[kt & 1];
        for (int ks2 = 0; ks2 < 2; ++ks2) {
            int ka = (ks2 * 32 + q * 8) ^ swz;
            int ks = kt * 2 + ks2;
            for (int nt = 0; nt < 8; ++nt) {
                short8 bf = *(const short8*)&src[(nt * 16 + ln) * 64 + ka];
                acc[0][nt] = __builtin_amdgcn_mfma_f32_16x16x32_bf16(a2[0][ks], bf, acc[0][nt], 0, 0, 0);
                acc[1][nt] = __builtin_amdgcn_mfma_f32_16x16x32_bf16(a2[1][ks], bf, acc[1][nt], 0, 0, 0);
            }
        }
    }

    // ---- Epilogue 2: ELU, dot W2, 16-lane reduce, sigmoid, store ----
    for (int mt = 0; mt < 2; ++mt) {
        float s0 = 0.f, s1 = 0.f, s2 = 0.f, s3 = 0.f;
        for (int nt = 0; nt < 8; ++nt) {
            float wv = W2v[nt * 16 + ln];
            float4v v = acc[mt][nt];
            float x;
            x = v[0]; x = x > 0.f ? x : (__expf(x) - 1.f); s0 += x * wv;
            x = v[1]; x = x > 0.f ? x : (__expf(x) - 1.f); s1 += x * wv;
            x = v[2]; x = x > 0.f ? x : (__expf(x) - 1.f); s2 += x * wv;
            x = v[3]; x = x > 0.f ? x : (__expf(x) - 1.f); s3 += x * wv;
        }
        for (int off = 1; off < 16; off <<= 1) {
            s0 += __shfl_xor(s0, off);
            s1 += __shfl_xor(s1, off);
            s2 += __shfl_xor(s2, off);
            s3 += __shfl_xor(s3, off);
        }
        if (ln < 4) {
            float sv = (ln == 0) ? s0 : (ln == 1) ? s1 : (ln == 2) ? s2 : s3;
            int e = e0 + wave * 32 + mt * 16 + q * 4 + ln;
            if (e < E_EDGES) {
                float z = sv + b2v[0];
                out[type * E_EDGES + e] = 1.f / (1.f + __expf(-z));
            }
        }
    }
}

extern "C" void kernel_launch(void* const* d_in, const int* in_sizes, int n_in,
                              void* d_out, int out_size, void* d_ws, size_t ws_size,
                              hipStream_t stream) {
    const float* user_emb = (const float*)d_in[0];
    const float* item_emb = (const float*)d_in[1];
    const int*   ei_ui    = (const int*)d_in[2];
    const int*   ei_iu    = (const int*)d_in[3];
    const float* W_bi_ui  = (const float*)d_in[4];
    const float* b_bi_ui  = (const float*)d_in[5];
    const float* W1_ui    = (const float*)d_in[6];
    const float* b1_ui    = (const float*)d_in[7];
    const float* W2_ui    = (const float*)d_in[8];
    const float* b2_ui    = (const float*)d_in[9];
    const float* W_bi_iu  = (const float*)d_in[10];
    const float* b_bi_iu  = (const float*)d_in[11];
    const float* W1_iu    = (const float*)d_in[12];
    const float* b1_iu    = (const float*)d_in[13];
    const float* W2_iu    = (const float*)d_in[14];
    const float* b2_iu    = (const float*)d_in[15];
    short* ws  = (short*)d_ws;
    short* tab = ws + 98304;
    float* out = (float*)d_out;

    const size_t need = 98304u * 2u + (size_t)2 * TAB_ELEMS * 2u;  // 51.4 MB

    hipLaunchKernelGGL(prep_all, dim3(1036, 2), dim3(256), 0, stream,
                       user_emb, item_emb, W_bi_ui, W1_ui, W_bi_iu, W1_iu, ws);
    if (ws_size >= need) {
        edge_decoder<true><<<dim3(NBLK, 2), dim3(256), 0, stream>>>(
            user_emb, item_emb, ei_ui, ei_iu,
            b_bi_ui, b1_ui, W2_ui, b2_ui,
            b_bi_iu, b1_iu, W2_iu, b2_iu,
            ws, tab, out);
    } else {
        edge_decoder<false><<<dim3(NBLK, 2), dim3(256), 0, stream>>>(
            user_emb, item_emb, ei_ui, ei_iu,
            b_bi_ui, b1_ui, W2_ui, b2_ui,
            b_bi_iu, b1_iu, W2_iu, b2_iu,
            ws, tab, out);
    }
}

// Round 8
// 250.841 us; speedup vs baseline: 1.0860x; 1.0303x over previous
//
#include <hip/hip_runtime.h>

typedef __attribute__((ext_vector_type(8))) short short8;
typedef __attribute__((ext_vector_type(4))) float float4v;
typedef __attribute__((ext_vector_type(4))) int int4v;

#define E_EDGES 300000
#define EPB 128                                 // edges per block (32 per wave)
#define NBLK ((E_EDGES + EPB - 1) / EPB)        // 2344 blocks per edge type
#define TAB_ELEMS 12800000                      // 100000 nodes x 128 feats

__device__ __forceinline__ short f2bf(float f) {
    unsigned u = __float_as_uint(f);
    return (short)((u + 0x7FFFu + ((u >> 16) & 1u)) >> 16);
}
__device__ __forceinline__ unsigned pk_bf16(float a, float b) {
    unsigned ua = __float_as_uint(a), ub = __float_as_uint(b);
    ua += 0x7FFFu + ((ua >> 16) & 1u);
    ub += 0x7FFFu + ((ub >> 16) & 1u);
    return __builtin_amdgcn_perm(ub, ua, 0x07060302);
}
__device__ __forceinline__ void cp16(const void* g, void* l) {
    __builtin_amdgcn_global_load_lds(
        (const __attribute__((address_space(1))) unsigned int*)g,
        (__attribute__((address_space(3))) unsigned int*)l, 16, 0, 0);
}

// ws layout (shorts):
//   weights in 128-k STAGES, [n=128][k=128] per stage, 16-B chunks XOR-swizzled:
//     chunk c (=kk>>3) stored at p = (c&8) | ((c ^ (n&7)) & 7)
//   [0..32768)      Wbi type0 (2 stages)   [32768..65536)  Wbi type1
//   [65536..81920)  W1  type0 (1 stage)    [81920..98304)  W1  type1
//   [98304..+12.8M) user_emb bf16          [..+25.6M)      item_emb bf16
__global__ void prep_all(const float* __restrict__ ue, const float* __restrict__ ie,
                         const float* __restrict__ Wbi_ui, const float* __restrict__ W1_ui,
                         const float* __restrict__ Wbi_iu, const float* __restrict__ W1_iu,
                         short* __restrict__ ws) {
    __shared__ short tr[64 * 68];
    const int t = blockIdx.y;
    const int tid = threadIdx.x;
    if (blockIdx.x < 1024) {                    // ---- streaming table conversion ----
        const float* src = t ? ie : ue;
        short* dst = ws + 98304 + (size_t)t * TAB_ELEMS;
        const int stride = 1024 * 256;
        for (int g = blockIdx.x * 256 + tid; g < TAB_ELEMS / 8; g += stride) {
            const float* p = src + (size_t)g * 8;
            float4v v0 = ((const float4v*)p)[0];
            float4v v1 = ((const float4v*)p)[1];
            int4v w = { (int)pk_bf16(v0[0], v0[1]), (int)pk_bf16(v0[2], v0[3]),
                        (int)pk_bf16(v1[0], v1[1]), (int)pk_bf16(v1[2], v1[3]) };
            *(int4v*)(dst + (size_t)g * 8) = w;
        }
        return;
    }
    // ---- weight transpose + swizzle: one 64k x 64n source tile per block ----
    const int m = blockIdx.x - 1024;            // 0..11
    const float* W; int k0, n0, obase, kbase;
    if (m < 8) {                                // Wbi (K=256, N=128)
        int kt = m >> 1, nh = m & 1;
        W = t ? Wbi_iu : Wbi_ui; k0 = kt * 64; n0 = nh * 64;
        obase = t * 32768 + (kt >> 1) * 16384;  // stage = kt>>1
        kbase = (kt & 1) * 64;                  // k-offset within stage
    } else {                                    // W1 (K=128, N=128), single stage
        int mm = m - 8; int kt = mm >> 1, nh = mm & 1;
        W = t ? W1_iu : W1_ui; k0 = kt * 64; n0 = nh * 64;
        obase = 65536 + t * 16384;
        kbase = kt * 64;
    }
    for (int it = 0; it < 16; ++it) {           // coalesced read (n contiguous)
        int flat = it * 256 + tid;
        int kk = flat >> 6, nn = flat & 63;
        tr[nn * 68 + kk] = f2bf(W[(size_t)(k0 + kk) * 128 + n0 + nn]);
    }
    __syncthreads();
    for (int it = 0; it < 16; ++it) {           // swizzled write
        int flat = it * 256 + tid;
        int nn = flat >> 6, kk = flat & 63;
        int n = n0 + nn;
        int kkst = kbase + kk;                  // k within stage (0..127)
        int c = kkst >> 3, co = kkst & 7;
        int p = (c & 8) | ((c ^ (n & 7)) & 7);
        ws[obase + n * 128 + p * 8 + co] = tr[nn * 68 + kk];
    }
}

template<bool BF16G>
__launch_bounds__(256, 3)
__global__ void edge_decoder(
    const float* __restrict__ user_emb, const float* __restrict__ item_emb,
    const int* __restrict__ ei_ui, const int* __restrict__ ei_iu,
    const float* __restrict__ b_bi_ui, const float* __restrict__ b1_ui,
    const float* __restrict__ W2_ui, const float* __restrict__ b2_ui,
    const float* __restrict__ b_bi_iu, const float* __restrict__ b1_iu,
    const float* __restrict__ W2_iu, const float* __restrict__ b2_iu,
    const short* __restrict__ ws, const short* __restrict__ tab,
    float* __restrict__ out)
{
    __shared__ short Blds[128 * 128];           // 32768 B: one 128-k weight stage
    __shared__ short Hlds[4 * 16 * 136];        // 17408 B per-wave H (16 rows, reused mt=0,1)

    const int type = blockIdx.y;
    const int e0 = blockIdx.x * EPB;
    const int tid = threadIdx.x;
    const int wave = tid >> 6, lane = tid & 63;
    const int q = lane >> 4, ln = lane & 15;

    const int*   ei   = type ? ei_iu : ei_ui;
    const float* bbi  = type ? b_bi_iu : b_bi_ui;
    const float* b1v  = type ? b1_iu : b1_ui;
    const float* W2v  = type ? W2_iu : W2_ui;
    const float* b2v  = type ? b2_iu : b2_ui;
    const short* WbiT = ws + type * 32768;
    const short* W1T  = ws + 65536 + type * 16384;

    // DMA weight stage 0 (Wbi k=0..127) -- overlaps the gather below
    for (int c = 0; c < 8; ++c)
        cp16(WbiT + c * 2048 + tid * 8, Blds + c * 2048 + tid * 8);

    // gather A fragments: a[mt][ks] elem j = e_cat[edge][32*ks + 8*q + j]
    short8 a[2][8];
    if (BF16G) {
        for (int mt = 0; mt < 2; ++mt) {
            int erow = e0 + wave * 32 + mt * 16 + ln;
            int safe = (erow < E_EDGES) ? erow : 0;
            const short* sp = tab + (size_t)(type ? TAB_ELEMS : 0) + (size_t)ei[safe] * 128;
            const short* dp = tab + (size_t)(type ? 0 : TAB_ELEMS) + (size_t)ei[E_EDGES + safe] * 128;
            for (int ks = 0; ks < 4; ++ks)
                a[mt][ks] = *(const short8*)(sp + ks * 32 + q * 8);
            for (int ks = 4; ks < 8; ++ks)
                a[mt][ks] = *(const short8*)(dp + (ks - 4) * 32 + q * 8);
        }
    } else {
        const float* srcT = type ? item_emb : user_emb;
        const float* dstT = type ? user_emb : item_emb;
        for (int mt = 0; mt < 2; ++mt) {
            int erow = e0 + wave * 32 + mt * 16 + ln;
            int safe = (erow < E_EDGES) ? erow : 0;
            int si = ei[safe], di = ei[E_EDGES + safe];
            for (int ks = 0; ks < 8; ++ks) {
                const float* p = (ks < 4) ? (srcT + (size_t)si * 128 + ks * 32 + q * 8)
                                          : (dstT + (size_t)di * 128 + (ks - 4) * 32 + q * 8);
                float4v v0 = ((const float4v*)p)[0];
                float4v v1 = ((const float4v*)p)[1];
                int4v w = { (int)pk_bf16(v0[0], v0[1]), (int)pk_bf16(v0[2], v0[3]),
                            (int)pk_bf16(v1[0], v1[1]), (int)pk_bf16(v1[2], v1[3]) };
                a[mt][ks] = *(short8*)&w;
            }
        }
    }

    // acc init = bias (column-only -> all 4 row-elems identical)
    float4v acc[2][8];
    for (int nt = 0; nt < 8; ++nt) {
        float bb = bbi[nt * 16 + ln];
        acc[0][nt] = (float4v){bb, bb, bb, bb};
        acc[1][nt] = acc[0][nt];
    }

    const int swz7 = ln & 7;
    // chunk offset for frag (ks2, q): c = ks2*4 + q; physical p = (c&8)|((c^swz7)&7)
#define KAOF(ks2) ((((((ks2) * 4 + q) & 8) | ((((ks2) * 4 + q) ^ swz7) & 7))) * 8)

    // ---- Layer 1 stage 0 (k=0..127, src row) ----
    __syncthreads();                            // stage 0 resident
    for (int ks2 = 0; ks2 < 4; ++ks2) {
        int ka = KAOF(ks2);
        for (int nt = 0; nt < 8; ++nt) {
            short8 bf = *(const short8*)&Blds[(nt * 16 + ln) * 128 + ka];
            acc[0][nt] = __builtin_amdgcn_mfma_f32_16x16x32_bf16(a[0][ks2], bf, acc[0][nt], 0, 0, 0);
            acc[1][nt] = __builtin_amdgcn_mfma_f32_16x16x32_bf16(a[1][ks2], bf, acc[1][nt], 0, 0, 0);
        }
    }
    __syncthreads();                            // all waves done with stage 0
    for (int c = 0; c < 8; ++c)                 // DMA stage 1 (Wbi k=128..255)
        cp16(WbiT + 16384 + c * 2048 + tid * 8, Blds + c * 2048 + tid * 8);

    // ---- Layer 1 stage 1 (k=128..255, dst row) ----
    __syncthreads();                            // stage 1 resident
    for (int ks2 = 0; ks2 < 4; ++ks2) {
        int ka = KAOF(ks2);
        for (int nt = 0; nt < 8; ++nt) {
            short8 bf = *(const short8*)&Blds[(nt * 16 + ln) * 128 + ka];
            acc[0][nt] = __builtin_amdgcn_mfma_f32_16x16x32_bf16(a[0][4 + ks2], bf, acc[0][nt], 0, 0, 0);
            acc[1][nt] = __builtin_amdgcn_mfma_f32_16x16x32_bf16(a[1][4 + ks2], bf, acc[1][nt], 0, 0, 0);
        }
    }
    __syncthreads();                            // all waves done with stage 1
    for (int c = 0; c < 8; ++c)                 // DMA W1 stage; lands under ep1's VALU
        cp16(W1T + c * 2048 + tid * 8, Blds + c * 2048 + tid * 8);

    // ---- Epilogue 1: ELU -> bf16 H, wave-local 16-row buffer reused mt=0,1 ----
    // C/D layout: col = ln (+16*nt) = hidden, row = q*4 + r = edge-in-tile
    short* Hw = Hlds + wave * (16 * 136);
    short8 a2[2][4];
    for (int mt = 0; mt < 2; ++mt) {
        for (int nt = 0; nt < 8; ++nt) {
            int col = nt * 16 + ln;
            float4v v = acc[mt][nt];
            for (int r = 0; r < 4; ++r) {
                float x = v[r];
                float h = x > 0.f ? x : (__expf(x) - 1.f);
                Hw[(q * 4 + r) * 136 + col] = f2bf(h);
            }
        }
        for (int ks = 0; ks < 4; ++ks)          // same-wave RAW, lgkmcnt-guarded
            a2[mt][ks] = *(const short8*)&Hw[ln * 136 + ks * 32 + q * 8];
    }

    for (int nt = 0; nt < 8; ++nt) {
        float bb = b1v[nt * 16 + ln];
        acc[0][nt] = (float4v){bb, bb, bb, bb};
        acc[1][nt] = acc[0][nt];
    }

    // ---- Layer 2: one 128-k stage ----
    __syncthreads();                            // W1 stage resident
    for (int ks2 = 0; ks2 < 4; ++ks2) {
        int ka = KAOF(ks2);
        for (int nt = 0; nt < 8; ++nt) {
            short8 bf = *(const short8*)&Blds[(nt * 16 + ln) * 128 + ka];
            acc[0][nt] = __builtin_amdgcn_mfma_f32_16x16x32_bf16(a2[0][ks2], bf, acc[0][nt], 0, 0, 0);
            acc[1][nt] = __builtin_amdgcn_mfma_f32_16x16x32_bf16(a2[1][ks2], bf, acc[1][nt], 0, 0, 0);
        }
    }
#undef KAOF

    // ---- Epilogue 2: ELU, dot W2, 16-lane reduce, sigmoid, store ----
    for (int mt = 0; mt < 2; ++mt) {
        float s0 = 0.f, s1 = 0.f, s2 = 0.f, s3 = 0.f;
        for (int nt = 0; nt < 8; ++nt) {
            float wv = W2v[nt * 16 + ln];
            float4v v = acc[mt][nt];
            float x;
            x = v[0]; x = x > 0.f ? x : (__expf(x) - 1.f); s0 += x * wv;
            x = v[1]; x = x > 0.f ? x : (__expf(x) - 1.f); s1 += x * wv;
            x = v[2]; x = x > 0.f ? x : (__expf(x) - 1.f); s2 += x * wv;
            x = v[3]; x = x > 0.f ? x : (__expf(x) - 1.f); s3 += x * wv;
        }
        for (int off = 1; off < 16; off <<= 1) {
            s0 += __shfl_xor(s0, off);
            s1 += __shfl_xor(s1, off);
            s2 += __shfl_xor(s2, off);
            s3 += __shfl_xor(s3, off);
        }
        if (ln < 4) {
            float sv = (ln == 0) ? s0 : (ln == 1) ? s1 : (ln == 2) ? s2 : s3;
            int e = e0 + wave * 32 + mt * 16 + q * 4 + ln;
            if (e < E_EDGES) {
                float z = sv + b2v[0];
                out[type * E_EDGES + e] = 1.f / (1.f + __expf(-z));
            }
        }
    }
}

extern "C" void kernel_launch(void* const* d_in, const int* in_sizes, int n_in,
                              void* d_out, int out_size, void* d_ws, size_t ws_size,
                              hipStream_t stream) {
    const float* user_emb = (const float*)d_in[0];
    const float* item_emb = (const float*)d_in[1];
    const int*   ei_ui    = (const int*)d_in[2];
    const int*   ei_iu    = (const int*)d_in[3];
    const float* W_bi_ui  = (const float*)d_in[4];
    const float* b_bi_ui  = (const float*)d_in[5];
    const float* W1_ui    = (const float*)d_in[6];
    const float* b1_ui    = (const float*)d_in[7];
    const float* W2_ui    = (const float*)d_in[8];
    const float* b2_ui    = (const float*)d_in[9];
    const float* W_bi_iu  = (const float*)d_in[10];
    const float* b_bi_iu  = (const float*)d_in[11];
    const float* W1_iu    = (const float*)d_in[12];
    const float* b1_iu    = (const float*)d_in[13];
    const float* W2_iu    = (const float*)d_in[14];
    const float* b2_iu    = (const float*)d_in[15];
    short* ws  = (short*)d_ws;
    short* tab = ws + 98304;
    float* out = (float*)d_out;

    const size_t need = 98304u * 2u + (size_t)2 * TAB_ELEMS * 2u;  // 51.4 MB

    hipLaunchKernelGGL(prep_all, dim3(1036, 2), dim3(256), 0, stream,
                       user_emb, item_emb, W_bi_ui, W1_ui, W_bi_iu, W1_iu, ws);
    if (ws_size >= need) {
        edge_decoder<true><<<dim3(NBLK, 2), dim3(256), 0, stream>>>(
            user_emb, item_emb, ei_ui, ei_iu,
            b_bi_ui, b1_ui, W2_ui, b2_ui,
            b_bi_iu, b1_iu, W2_iu, b2_iu,
            ws, tab, out);
    } else {
        edge_decoder<false><<<dim3(NBLK, 2), dim3(256), 0, stream>>>(
            user_emb, item_emb, ei_ui, ei_iu,
            b_bi_ui, b1_ui, W2_ui, b2_ui,
            b_bi_iu, b1_iu, W2_iu, b2_iu,
            ws, tab, out);
    }
}